// Round 4
// baseline (337.088 us; speedup 1.0000x reference)
//
#include <hip/hip_runtime.h>

// Problem constants (match reference)
constexpr int BB  = 8;
constexpr int NN  = 2048;
constexpr int IND = 128;
constexpr int HD  = 64;
constexpr float LN_EPS = 1e-5f;
constexpr float SLOPE  = 0.2f;

typedef _Float16 half8 __attribute__((ext_vector_type(8)));
typedef _Float16 half4 __attribute__((ext_vector_type(4)));
typedef float    f32x4 __attribute__((ext_vector_type(4)));

__device__ __forceinline__ float wave_sum(float v) {
    #pragma unroll
    for (int off = 32; off > 0; off >>= 1) v += __shfl_xor(v, off);
    return v;
}
__device__ __forceinline__ float wave_max(float v) {
    #pragma unroll
    for (int off = 32; off > 0; off >>= 1) v = fmaxf(v, __shfl_xor(v, off));
    return v;
}

// ---------------------------------------------------------------------------
// Kernel 1: gated inputs (unchanged math) + adj bit-pack phase.
// Wave owns 8 rows for BOTH phases.  Pack layout (lane-local, no cross-lane):
//   mask[row][lane] bit (4c+d) = adj[row][c*256 + 4*lane + d]
// which is exactly what k_attn's lane (handling j = c*256+4*lane+d) consumes.
// ---------------------------------------------------------------------------
__global__ __launch_bounds__(256) void k_gates_pack(
    const int* __restrict__ adj,
    const float* __restrict__ x, const float* __restrict__ h,
    const float* __restrict__ X2H, const float* __restrict__ H2H,
    const float* __restrict__ a,
    float* __restrict__ Wh_out, _Float16* __restrict__ Whh2,
    float* __restrict__ Wh1, float* __restrict__ Wh2,
    unsigned* __restrict__ mask)
{
    const int lane = threadIdx.x & 63;
    const int wid  = threadIdx.x >> 6;
    const int base = (blockIdx.x * 4 + wid) * 8;   // 8 rows per wave

    // ---- phase 1: gates ----
    float gx0[8] = {0}, gx1[8] = {0}, gx2[8] = {0};
    float gh0[8] = {0}, gh1[8] = {0}, gh2[8] = {0};

    for (int d4 = 0; d4 < IND; d4 += 4) {
        float w0[4], w1[4], w2[4];
        #pragma unroll
        for (int dd = 0; dd < 4; ++dd) {
            const float* wp = X2H + (size_t)(d4 + dd) * 192;
            w0[dd] = wp[lane]; w1[dd] = wp[64 + lane]; w2[dd] = wp[128 + lane];
        }
        #pragma unroll
        for (int rr = 0; rr < 8; ++rr) {
            f32x4 xv = *(const f32x4*)(x + (size_t)(base + rr) * IND + d4);
            #pragma unroll
            for (int dd = 0; dd < 4; ++dd) {
                gx0[rr] = fmaf(xv[dd], w0[dd], gx0[rr]);
                gx1[rr] = fmaf(xv[dd], w1[dd], gx1[rr]);
                gx2[rr] = fmaf(xv[dd], w2[dd], gx2[rr]);
            }
        }
    }
    for (int d4 = 0; d4 < HD; d4 += 4) {
        float w0[4], w1[4], w2[4];
        #pragma unroll
        for (int dd = 0; dd < 4; ++dd) {
            const float* wp = H2H + (size_t)(d4 + dd) * 192;
            w0[dd] = wp[lane]; w1[dd] = wp[64 + lane]; w2[dd] = wp[128 + lane];
        }
        #pragma unroll
        for (int rr = 0; rr < 8; ++rr) {
            f32x4 hv = *(const f32x4*)(h + (size_t)(base + rr) * HD + d4);
            #pragma unroll
            for (int dd = 0; dd < 4; ++dd) {
                gh0[rr] = fmaf(hv[dd], w0[dd], gh0[rr]);
                gh1[rr] = fmaf(hv[dd], w1[dd], gh1[rr]);
                gh2[rr] = fmaf(hv[dd], w2[dd], gh2[rr]);
            }
        }
    }

    const float a0 = a[lane], a1 = a[64 + lane];
    half8 p8;
    for (int rr = 0; rr < 8; ++rr) {
        const int row = base + rr;
        const float hr = h[(size_t)row * HD + lane];
        const float rg = 1.f / (1.f + __expf(-(gx0[rr] + gh0[rr])));
        const float ig = 1.f / (1.f + __expf(-(gx1[rr] + gh1[rr])));
        float irh = gx2[rr] + rg * gh2[rr];
        const float mu = wave_sum(irh) * (1.f / 64.f);
        const float dv = irh - mu;
        const float var = wave_sum(dv * dv) * (1.f / 64.f);
        const float ng = tanhf(dv * rsqrtf(var + LN_EPS));
        const float wh = ng + ig * (hr - ng);
        Wh_out[(size_t)row * HD + lane] = wh;
        p8[rr] = (_Float16)wh;
        const float d1 = wave_sum(wh * a0);
        const float d2 = wave_sum(wh * a1);
        if (lane == 0) { Wh1[row] = d1; Wh2[row] = d2; }
    }
    *(half8*)(Whh2 + ((size_t)(base >> 3) * 64 + lane) * 8) = p8;

    // ---- phase 2: pack this wave's 8 adj rows (128 MB stream -> 4 MB) ----
    #pragma unroll 2
    for (int rr = 0; rr < 8; ++rr) {
        const int row = base + rr;
        const int4* __restrict__ arow = (const int4*)(adj + (size_t)row * NN);
        int4 av[8];
        #pragma unroll
        for (int c = 0; c < 8; ++c) av[c] = arow[c * 64 + lane];  // 8 in flight
        unsigned w = 0;
        #pragma unroll
        for (int c = 0; c < 8; ++c) {
            w |= (unsigned)(av[c].x != 0) << (4 * c + 0);
            w |= (unsigned)(av[c].y != 0) << (4 * c + 1);
            w |= (unsigned)(av[c].z != 0) << (4 * c + 2);
            w |= (unsigned)(av[c].w != 0) << (4 * c + 3);
        }
        mask[(size_t)row * 64 + lane] = w;
    }
}

// ---------------------------------------------------------------------------
// Kernel 2: attention from the bitmask — no adj traffic at all.
// One wave = 16 query rows.  All inputs L2/L3-resident (mask 4 MB,
// Whh2 2 MB/batch, Wh1/Wh2 tiny).  Per K-chunk of 256: Phase A nibble-mask
// scores -> P (fp16) in wave-private LDS; Phase B: 8 k-steps, cc INNER so
// the 4 accumulator chains interleave (1 wave/SIMD cannot hide a chained
// MFMA otherwise); A-fragment ds_read hoisted (1 per k-step, not 4).
// ---------------------------------------------------------------------------
constexpr int KC  = 256;
constexpr int PST = KC + 8;

__global__ __launch_bounds__(64, 1) void k_attn(
    const unsigned* __restrict__ mask,   // [B*N][64]
    const _Float16* __restrict__ Whh2,   // [B][N/8][64][8]
    const float* __restrict__ Wh1, const float* __restrict__ Wh2,
    float* __restrict__ hp)
{
    __shared__ __align__(16) _Float16 Pbuf[16 * PST];   // 8448 B, wave-private

    const int lane = threadIdx.x;            // 0..63
    const int b    = blockIdx.x >> 7;
    const int i0   = (blockIdx.x & 127) * 16;
    const int m    = lane & 15;
    const int q    = lane >> 4;

    // Wh2 register cache: wv[c][d] = Wh2[b][c*256 + 4*lane + d]
    f32x4 wv[8];
    const f32x4* __restrict__ w2v = (const f32x4*)(Wh2 + (size_t)b * NN);
    #pragma unroll
    for (int k = 0; k < 8; ++k) wv[k] = w2v[lane + 64 * k];

    // mask words for the 16 rows (one uint32 per row per lane, loaded once)
    unsigned mw[16];
    #pragma unroll
    for (int r = 0; r < 16; ++r)
        mw[r] = mask[(size_t)(b * NN + i0 + r) * 64 + lane];

    // batch-wide max of Wh2 — wave-local
    float mx = -3e38f;
    #pragma unroll
    for (int k = 0; k < 8; ++k)
        mx = fmaxf(mx, fmaxf(fmaxf(wv[k][0], wv[k][1]), fmaxf(wv[k][2], wv[k][3])));
    const float M = wave_max(mx);

    float w1r[16], cr[16];
    #pragma unroll
    for (int r = 0; r < 16; ++r) {
        w1r[r] = Wh1[b * NN + i0 + r];
        const float t0 = w1r[r] + M;
        cr[r] = (t0 > 0.f) ? t0 : SLOPE * t0;   // exact row upper bound
    }

    const half8* __restrict__ Wp = (const half8*)(Whh2 + (size_t)b * NN * HD);

    float sacc[16];
    #pragma unroll
    for (int r = 0; r < 16; ++r) sacc[r] = 0.f;
    f32x4 acc[4];
    #pragma unroll
    for (int cc = 0; cc < 4; ++cc) acc[cc] = (f32x4){0.f, 0.f, 0.f, 0.f};

    for (int c = 0; c < 8; ++c) {
        // ---- Phase A: P chunk from mask nibbles ----
        #pragma unroll
        for (int r = 0; r < 16; ++r) {
            const unsigned nib = (mw[r] >> (4 * c)) & 0xFu;
            half4 ph;
            float s = 0.f;
            #pragma unroll
            for (int d = 0; d < 4; ++d) {
                const float t = w1r[r] + wv[c][d];
                const float e = (t > 0.f) ? t : SLOPE * t;
                const float p = (nib & (1u << d)) ? __expf(e - cr[r]) : 0.f;
                s += p;
                ph[d] = (_Float16)p;
            }
            sacc[r] += s;
            *(half4*)&Pbuf[r * PST + 4 * lane] = ph;     // ds_write_b64
        }
        __syncthreads();   // 1-wave workgroup: elided to waitcnt ordering

        // ---- Phase B: 16x64 += P[16 x 256] @ Wh[256 x 64] ----
        #pragma unroll
        for (int k8 = 0; k8 < 8; ++k8) {
            const half8 a8 = *(const half8*)&Pbuf[m * PST + k8 * 32 + q * 8];
            #pragma unroll
            for (int cc = 0; cc < 4; ++cc) {
                const half8 b8 = Wp[(size_t)(c * 32 + k8 * 4 + q) * 64 + cc * 16 + m];
                acc[cc] = __builtin_amdgcn_mfma_f32_16x16x32_f16(a8, b8, acc[cc], 0, 0, 0);
            }
        }
        __syncthreads();   // elided; WAR guard before next chunk's writes
    }

    // ---- epilogue ----
    float linv[16];
    #pragma unroll
    for (int r = 0; r < 16; ++r) linv[r] = 1.f / wave_sum(sacc[r]);

    #pragma unroll
    for (int cc = 0; cc < 4; ++cc) {
        #pragma unroll
        for (int r2 = 0; r2 < 4; ++r2) {
            float l = (q == 0) ? linv[r2]
                    : (q == 1) ? linv[4 + r2]
                    : (q == 2) ? linv[8 + r2]
                               : linv[12 + r2];
            const int irow = q * 4 + r2;
            hp[((size_t)b * NN + i0 + irow) * HD + cc * 16 + m] = acc[cc][r2] * l;
        }
    }
}

// ---------------------------------------------------------------------------
extern "C" void kernel_launch(void* const* d_in, const int* in_sizes, int n_in,
                              void* d_out, int out_size, void* d_ws, size_t ws_size,
                              hipStream_t stream) {
    const int*   adj = (const int*)d_in[0];
    const float* x   = (const float*)d_in[1];
    const float* h   = (const float*)d_in[2];
    const float* X2H = (const float*)d_in[3];
    const float* H2H = (const float*)d_in[4];
    const float* a   = (const float*)d_in[5];

    float* out = (float*)d_out;
    float* hp  = out;                              // h_prime [8][2048][64]
    float* Wh  = out + (size_t)BB * NN * HD;       // Wh      [8][2048][64]

    float*    Wh1  = (float*)d_ws;                       // [B*N]
    float*    Wh2  = Wh1 + BB * NN;                      // [B*N]
    _Float16* Whh2 = (_Float16*)(Wh2 + BB * NN);         // [B][N/8][64][8]
    unsigned* mask = (unsigned*)(Whh2 + (size_t)BB * NN * HD);  // [B*N][64]

    k_gates_pack<<<dim3((BB * NN) / 32), dim3(256), 0, stream>>>(
        adj, x, h, X2H, H2H, a, Wh, Whh2, Wh1, Wh2, mask);
    k_attn<<<dim3(BB * (NN / 16)), dim3(64), 0, stream>>>(
        mask, Whh2, Wh1, Wh2, hp);
}

// Round 5
// 304.850 us; speedup vs baseline: 1.1058x; 1.1058x over previous
//
#include <hip/hip_runtime.h>

// Problem constants (match reference)
constexpr int BB  = 8;
constexpr int NN  = 2048;
constexpr int IND = 128;
constexpr int HD  = 64;
constexpr float LN_EPS = 1e-5f;
constexpr float SLOPE  = 0.2f;

typedef _Float16 half8 __attribute__((ext_vector_type(8)));
typedef _Float16 half4 __attribute__((ext_vector_type(4)));
typedef float    f32x4 __attribute__((ext_vector_type(4)));

__device__ __forceinline__ float wave_sum(float v) {
    #pragma unroll
    for (int off = 32; off > 0; off >>= 1) v += __shfl_xor(v, off);
    return v;
}
__device__ __forceinline__ float wave_max(float v) {
    #pragma unroll
    for (int off = 32; off > 0; off >>= 1) v = fmaxf(v, __shfl_xor(v, off));
    return v;
}

// ---------------------------------------------------------------------------
// Kernel 0: adj bit-pack, pure stream.  2 rows/wave -> 8192 waves (32/CU).
//   mask[row][lane] bit (4c+d) = adj[row][c*256 + 4*lane + d]
// ---------------------------------------------------------------------------
__global__ __launch_bounds__(256, 8) void k_pack(
    const int* __restrict__ adj, unsigned* __restrict__ mask)
{
    const int lane = threadIdx.x & 63;
    const int wave = blockIdx.x * 4 + (threadIdx.x >> 6);
    const int row0 = wave * 2;

    #pragma unroll
    for (int rr = 0; rr < 2; ++rr) {
        const int row = row0 + rr;
        const int4* __restrict__ arow = (const int4*)(adj + (size_t)row * NN);
        int4 av[8];
        #pragma unroll
        for (int c = 0; c < 8; ++c) av[c] = arow[c * 64 + lane];  // coalesced, 8 in flight
        unsigned w = 0;
        #pragma unroll
        for (int c = 0; c < 8; ++c) {
            w |= (unsigned)(av[c].x != 0) << (4 * c + 0);
            w |= (unsigned)(av[c].y != 0) << (4 * c + 1);
            w |= (unsigned)(av[c].z != 0) << (4 * c + 2);
            w |= (unsigned)(av[c].w != 0) << (4 * c + 3);
        }
        mask[(size_t)row * 64 + lane] = w;
    }
}

// ---------------------------------------------------------------------------
// Kernel 1: gated inputs.  4 rows/wave -> 4096 waves (16/CU).
// Produces Wh (f32 output), Whh2 (fp16 k-packed [B][N/8][64][8]), Wh1, Wh2.
// Two waves fill one 8-pack (half4 store at offset base&7).
// ---------------------------------------------------------------------------
__global__ __launch_bounds__(256, 4) void k_gates(
    const float* __restrict__ x, const float* __restrict__ h,
    const float* __restrict__ X2H, const float* __restrict__ H2H,
    const float* __restrict__ a,
    float* __restrict__ Wh_out, _Float16* __restrict__ Whh2,
    float* __restrict__ Wh1, float* __restrict__ Wh2)
{
    const int lane = threadIdx.x & 63;
    const int wid  = threadIdx.x >> 6;
    const int base = (blockIdx.x * 4 + wid) * 4;   // 4 rows per wave

    float gx0[4] = {0}, gx1[4] = {0}, gx2[4] = {0};
    float gh0[4] = {0}, gh1[4] = {0}, gh2[4] = {0};

    for (int d4 = 0; d4 < IND; d4 += 4) {
        float w0[4], w1[4], w2[4];
        #pragma unroll
        for (int dd = 0; dd < 4; ++dd) {
            const float* wp = X2H + (size_t)(d4 + dd) * 192;
            w0[dd] = wp[lane]; w1[dd] = wp[64 + lane]; w2[dd] = wp[128 + lane];
        }
        #pragma unroll
        for (int rr = 0; rr < 4; ++rr) {
            f32x4 xv = *(const f32x4*)(x + (size_t)(base + rr) * IND + d4);
            #pragma unroll
            for (int dd = 0; dd < 4; ++dd) {
                gx0[rr] = fmaf(xv[dd], w0[dd], gx0[rr]);
                gx1[rr] = fmaf(xv[dd], w1[dd], gx1[rr]);
                gx2[rr] = fmaf(xv[dd], w2[dd], gx2[rr]);
            }
        }
    }
    for (int d4 = 0; d4 < HD; d4 += 4) {
        float w0[4], w1[4], w2[4];
        #pragma unroll
        for (int dd = 0; dd < 4; ++dd) {
            const float* wp = H2H + (size_t)(d4 + dd) * 192;
            w0[dd] = wp[lane]; w1[dd] = wp[64 + lane]; w2[dd] = wp[128 + lane];
        }
        #pragma unroll
        for (int rr = 0; rr < 4; ++rr) {
            f32x4 hv = *(const f32x4*)(h + (size_t)(base + rr) * HD + d4);
            #pragma unroll
            for (int dd = 0; dd < 4; ++dd) {
                gh0[rr] = fmaf(hv[dd], w0[dd], gh0[rr]);
                gh1[rr] = fmaf(hv[dd], w1[dd], gh1[rr]);
                gh2[rr] = fmaf(hv[dd], w2[dd], gh2[rr]);
            }
        }
    }

    const float a0 = a[lane], a1 = a[64 + lane];
    half4 p4;
    for (int rr = 0; rr < 4; ++rr) {
        const int row = base + rr;
        const float hr = h[(size_t)row * HD + lane];
        const float rg = 1.f / (1.f + __expf(-(gx0[rr] + gh0[rr])));
        const float ig = 1.f / (1.f + __expf(-(gx1[rr] + gh1[rr])));
        float irh = gx2[rr] + rg * gh2[rr];
        const float mu = wave_sum(irh) * (1.f / 64.f);
        const float dv = irh - mu;
        const float var = wave_sum(dv * dv) * (1.f / 64.f);
        const float ng = tanhf(dv * rsqrtf(var + LN_EPS));
        const float wh = ng + ig * (hr - ng);
        Wh_out[(size_t)row * HD + lane] = wh;
        p4[rr] = (_Float16)wh;
        const float d1 = wave_sum(wh * a0);
        const float d2 = wave_sum(wh * a1);
        if (lane == 0) { Wh1[row] = d1; Wh2[row] = d2; }
    }
    *(half4*)(Whh2 + ((size_t)(base >> 3) * 64 + lane) * 8 + (base & 7)) = p4;
}

// ---------------------------------------------------------------------------
// Kernel 2: attention from bitmask, K-split across 4 waves per block.
// Block = 16 query rows; wave w owns K-chunks {2w, 2w+1} (KC=256 each):
//   Phase A: nibble-mask scores -> P chunk (fp16) in wave-private LDS slice
//   Phase B: 8 k-steps x 4 col-chunk MFMAs, partial acc per wave
// End: partial acc + row-sums combined via LDS (accbuf aliases dead P area).
// 16 waves/CU (LDS 34KB -> 4 blocks/CU), MFMA latency hidden by 4 waves/SIMD.
// ---------------------------------------------------------------------------
constexpr int KC  = 256;
constexpr int PST = KC + 8;

__global__ __launch_bounds__(256, 4) void k_attn(
    const unsigned* __restrict__ mask,   // [B*N][64]
    const _Float16* __restrict__ Whh2,   // [B][N/8][64][8]
    const float* __restrict__ Wh1, const float* __restrict__ Wh2,
    float* __restrict__ hp)
{
    __shared__ __align__(16) char smem[4 * 16 * PST * 2];   // 33792 B
    __shared__ float ssum[4][16];
    __shared__ float redb[4];

    const int tid  = threadIdx.x;
    const int lane = tid & 63;
    const int w    = tid >> 6;               // wave id in block
    const int b    = blockIdx.x >> 7;
    const int i0   = (blockIdx.x & 127) * 16;
    const int m    = lane & 15;
    const int q    = lane >> 4;

    _Float16* __restrict__ Pw = (_Float16*)smem + w * 16 * PST;  // wave-private

    // Wh2 register cache for this wave's 2 chunks
    const f32x4* __restrict__ w2v = (const f32x4*)(Wh2 + (size_t)b * NN);
    f32x4 wv[2];
    #pragma unroll
    for (int t = 0; t < 2; ++t) wv[t] = w2v[(2 * w + t) * 64 + lane];

    // batch-wide max of Wh2: per-wave partial (over its 512) + block reduce
    float mx = fmaxf(fmaxf(wv[0][0], wv[0][1]), fmaxf(wv[0][2], wv[0][3]));
    mx = fmaxf(mx, fmaxf(fmaxf(wv[1][0], wv[1][1]), fmaxf(wv[1][2], wv[1][3])));
    mx = wave_max(mx);
    if (lane == 0) redb[w] = mx;
    __syncthreads();
    const float M = fmaxf(fmaxf(redb[0], redb[1]), fmaxf(redb[2], redb[3]));

    // mask words + per-row shift (identical across waves: same M, same Wh1)
    unsigned mw[16];
    float w1r[16], cr[16];
    #pragma unroll
    for (int r = 0; r < 16; ++r) {
        mw[r]  = mask[(size_t)(b * NN + i0 + r) * 64 + lane];
        w1r[r] = Wh1[b * NN + i0 + r];
        const float t0 = w1r[r] + M;
        cr[r] = (t0 > 0.f) ? t0 : SLOPE * t0;   // exact row upper bound
    }

    const half8* __restrict__ Wp = (const half8*)(Whh2 + (size_t)b * NN * HD);

    float sacc[16];
    #pragma unroll
    for (int r = 0; r < 16; ++r) sacc[r] = 0.f;
    f32x4 acc[4];
    #pragma unroll
    for (int cc = 0; cc < 4; ++cc) acc[cc] = (f32x4){0.f, 0.f, 0.f, 0.f};

    #pragma unroll
    for (int t = 0; t < 2; ++t) {
        const int c = 2 * w + t;
        // ---- Phase A: P chunk from mask nibbles into wave-private slice ----
        #pragma unroll
        for (int r = 0; r < 16; ++r) {
            const unsigned nib = (mw[r] >> (4 * c)) & 0xFu;
            half4 ph;
            float s = 0.f;
            #pragma unroll
            for (int d = 0; d < 4; ++d) {
                const float tt = w1r[r] + wv[t][d];
                const float e = (tt > 0.f) ? tt : SLOPE * tt;
                const float p = (nib & (1u << d)) ? __expf(e - cr[r]) : 0.f;
                s += p;
                ph[d] = (_Float16)p;
            }
            sacc[r] += s;
            *(half4*)&Pw[r * PST + 4 * lane] = ph;     // ds_write_b64
        }
        __syncthreads();   // aligned across waves (same trip count)

        // ---- Phase B: partial 16x64 += P[16 x 256] @ Wh[256 x 64] ----
        #pragma unroll
        for (int k8 = 0; k8 < 8; ++k8) {
            const half8 a8 = *(const half8*)&Pw[m * PST + k8 * 32 + q * 8];
            #pragma unroll
            for (int cc = 0; cc < 4; ++cc) {
                const half8 b8 = Wp[(size_t)(c * 32 + k8 * 4 + q) * 64 + cc * 16 + m];
                acc[cc] = __builtin_amdgcn_mfma_f32_16x16x32_f16(a8, b8, acc[cc], 0, 0, 0);
            }
        }
        __syncthreads();   // WAR guard before next chunk's P writes
    }

    // ---- combine partials across the 4 waves ----
    // per-wave row sums
    #pragma unroll
    for (int r = 0; r < 16; ++r) {
        const float s = wave_sum(sacc[r]);
        if (lane == 0) ssum[w][r] = s;
    }
    // acc partials into LDS (aliases the now-dead P region; barrier above
    // guarantees all Phase-B reads finished)
    float* __restrict__ accb = (float*)smem;     // [4][64][4] f32x4
    #pragma unroll
    for (int cc = 0; cc < 4; ++cc)
        *(f32x4*)&accb[((w * 64 + lane) * 4 + cc) * 4] = acc[cc];
    __syncthreads();

    // wave w reduces col-chunk cc=w over the 4 partials
    f32x4 tot = (f32x4){0.f, 0.f, 0.f, 0.f};
    #pragma unroll
    for (int wp = 0; wp < 4; ++wp) {
        const f32x4 t4 = *(const f32x4*)&accb[((wp * 64 + lane) * 4 + w) * 4];
        tot[0] += t4[0]; tot[1] += t4[1]; tot[2] += t4[2]; tot[3] += t4[3];
    }
    #pragma unroll
    for (int r2 = 0; r2 < 4; ++r2) {
        const int irow = q * 4 + r2;
        const float S = ssum[0][irow] + ssum[1][irow] + ssum[2][irow] + ssum[3][irow];
        hp[((size_t)b * NN + i0 + irow) * HD + w * 16 + m] = tot[r2] / S;
    }
}

// ---------------------------------------------------------------------------
extern "C" void kernel_launch(void* const* d_in, const int* in_sizes, int n_in,
                              void* d_out, int out_size, void* d_ws, size_t ws_size,
                              hipStream_t stream) {
    const int*   adj = (const int*)d_in[0];
    const float* x   = (const float*)d_in[1];
    const float* h   = (const float*)d_in[2];
    const float* X2H = (const float*)d_in[3];
    const float* H2H = (const float*)d_in[4];
    const float* a   = (const float*)d_in[5];

    float* out = (float*)d_out;
    float* hp  = out;                              // h_prime [8][2048][64]
    float* Wh  = out + (size_t)BB * NN * HD;       // Wh      [8][2048][64]

    float*    Wh1  = (float*)d_ws;                       // [B*N]
    float*    Wh2  = Wh1 + BB * NN;                      // [B*N]
    _Float16* Whh2 = (_Float16*)(Wh2 + BB * NN);         // [B][N/8][64][8]
    unsigned* mask = (unsigned*)(Whh2 + (size_t)BB * NN * HD);  // [B*N][64]

    k_pack<<<dim3((BB * NN) / 8), dim3(256), 0, stream>>>(adj, mask);
    k_gates<<<dim3((BB * NN) / 16), dim3(256), 0, stream>>>(
        x, h, X2H, H2H, a, Wh, Whh2, Wh1, Wh2);
    k_attn<<<dim3(BB * (NN / 16)), dim3(256), 0, stream>>>(
        mask, Whh2, Wh1, Wh2, hp);
}

// Round 6
// 289.090 us; speedup vs baseline: 1.1660x; 1.0545x over previous
//
#include <hip/hip_runtime.h>

// Problem constants (match reference)
constexpr int BB  = 8;
constexpr int NN  = 2048;
constexpr int IND = 128;
constexpr int HD  = 64;
constexpr float LN_EPS = 1e-5f;
constexpr float SLOPE  = 0.2f;

typedef _Float16 half8 __attribute__((ext_vector_type(8)));
typedef _Float16 half4 __attribute__((ext_vector_type(4)));
typedef float    f32x4 __attribute__((ext_vector_type(4)));

__device__ __forceinline__ float wave_sum(float v) {
    #pragma unroll
    for (int off = 32; off > 0; off >>= 1) v += __shfl_xor(v, off);
    return v;
}
__device__ __forceinline__ float wave_max(float v) {
    #pragma unroll
    for (int off = 32; off > 0; off >>= 1) v = fmaxf(v, __shfl_xor(v, off));
    return v;
}

// ---------------------------------------------------------------------------
// Kernel 0: build Wt[256 cols][192 k] fp16, k-major, for the fused gates GEMM
// on input [x|h] (K=192).  Output cols:
//   [0,64):    r-gate  = X2H[:, c]      (k<128)  + H2H[:, c]       (k>=128)
//   [64,128):  i-gate  = X2H[:, c]      (k<128)  + H2H[:, c]       (k>=128)
//   [128,192): i_n     = X2H[:, c]      (k<128)  + 0               (k>=128)
//   [192,256): h_n     = 0              (k<128)  + H2H[:, c-64]    (k>=128)
// ---------------------------------------------------------------------------
__global__ void k_prep(const float* __restrict__ X2H, const float* __restrict__ H2H,
                       _Float16* __restrict__ Wt)
{
    const int tot = 256 * 192;
    for (int idx = blockIdx.x * 256 + threadIdx.x; idx < tot; idx += gridDim.x * 256) {
        const int col = idx / 192, k = idx % 192;
        float v;
        if (col < 128)       v = (k < 128) ? X2H[(size_t)k * 192 + col]
                                           : H2H[(size_t)(k - 128) * 192 + col];
        else if (col < 192)  v = (k < 128) ? X2H[(size_t)k * 192 + col] : 0.f;
        else                 v = (k >= 128) ? H2H[(size_t)(k - 128) * 192 + (col - 64)] : 0.f;
        Wt[idx] = (_Float16)v;
    }
}

// ---------------------------------------------------------------------------
// Kernel 1: gates via fp16 MFMA.  Block = 16 rows x 4 waves; wave w computes
// output cols [w*64, w*64+64) of the 256-col padded GEMM (A = [x|h] fp16,
// B = Wt).  Weights read: 24 half8/wave (18 KB, L1-resident) vs 147 KB
// re-streamed in the old FMA version.  Epilogue via LDS bounce, lane = col.
// ---------------------------------------------------------------------------
__global__ __launch_bounds__(256, 4) void k_gates(
    const float* __restrict__ x, const float* __restrict__ h,
    const _Float16* __restrict__ Wt, const float* __restrict__ a,
    float* __restrict__ Wh_out, _Float16* __restrict__ Whh2,
    float* __restrict__ Wh1, float* __restrict__ Wh2)
{
    __shared__ float gbuf[16][260];   // 16 rows x 256 cols (+4 pad), 16.6 KB

    const int tid = threadIdx.x, lane = tid & 63, w = tid >> 6;
    const int m = lane & 15, q = lane >> 4;
    const int row0 = blockIdx.x * 16;

    f32x4 acc[4];
    #pragma unroll
    for (int ct = 0; ct < 4; ++ct) acc[ct] = (f32x4){0.f, 0.f, 0.f, 0.f};

    #pragma unroll
    for (int kc = 0; kc < 6; ++kc) {
        // A-fragment: input[row0+m][kc*32 + q*8 .. +7] as fp16
        half8 a8;
        if (kc < 4) {
            const float* xp = x + (size_t)(row0 + m) * IND + kc * 32 + q * 8;
            const f32x4 v0 = *(const f32x4*)xp;
            const f32x4 v1 = *(const f32x4*)(xp + 4);
            #pragma unroll
            for (int j = 0; j < 4; ++j) { a8[j] = (_Float16)v0[j]; a8[4 + j] = (_Float16)v1[j]; }
        } else {
            const float* hp_ = h + (size_t)(row0 + m) * HD + (kc - 4) * 32 + q * 8;
            const f32x4 v0 = *(const f32x4*)hp_;
            const f32x4 v1 = *(const f32x4*)(hp_ + 4);
            #pragma unroll
            for (int j = 0; j < 4; ++j) { a8[j] = (_Float16)v0[j]; a8[4 + j] = (_Float16)v1[j]; }
        }
        #pragma unroll
        for (int ct = 0; ct < 4; ++ct) {
            const half8 b8 = *(const half8*)(Wt + ((size_t)(w * 64 + ct * 16 + m) * 192 + kc * 32 + q * 8));
            acc[ct] = __builtin_amdgcn_mfma_f32_16x16x32_f16(a8, b8, acc[ct], 0, 0, 0);
        }
    }

    // D -> LDS: row = q*4+r2, col = w*64 + ct*16 + m
    #pragma unroll
    for (int ct = 0; ct < 4; ++ct)
        #pragma unroll
        for (int r2 = 0; r2 < 4; ++r2)
            gbuf[q * 4 + r2][w * 64 + ct * 16 + m] = acc[ct][r2];
    __syncthreads();

    // epilogue: wave w owns rows w*4..w*4+3, lane = col (0..63)
    const float a0 = a[lane], a1 = a[64 + lane];
    half4 p4;
    const int grow0 = row0 + w * 4;
    #pragma unroll
    for (int r = 0; r < 4; ++r) {
        const int row = w * 4 + r;
        const int grow = row0 + row;
        const float g0 = gbuf[row][lane];
        const float g1 = gbuf[row][64 + lane];
        const float g2 = gbuf[row][128 + lane];
        const float g3 = gbuf[row][192 + lane];
        const float rg = 1.f / (1.f + __expf(-g0));
        const float ig = 1.f / (1.f + __expf(-g1));
        const float irh = g2 + rg * g3;
        const float mu = wave_sum(irh) * (1.f / 64.f);
        const float dv = irh - mu;
        const float var = wave_sum(dv * dv) * (1.f / 64.f);
        const float ng = tanhf(dv * rsqrtf(var + LN_EPS));
        const float hr = h[(size_t)grow * HD + lane];
        const float wh = ng + ig * (hr - ng);
        Wh_out[(size_t)grow * HD + lane] = wh;
        p4[r] = (_Float16)wh;
        const float d1 = wave_sum(wh * a0);
        const float d2 = wave_sum(wh * a1);
        if (lane == 0) { Wh1[grow] = d1; Wh2[grow] = d2; }
    }
    // fp16 k-pack store: rows grow0..grow0+3 -> slot (grow0&7) = (w&1)*4
    *(half4*)(Whh2 + ((size_t)(grow0 >> 3) * 64 + lane) * 8 + (w & 1) * 4) = p4;
}

// ---------------------------------------------------------------------------
// Kernel 2: attention, direct adj stream (no pack pass — adj crosses HBM once
// either way).  Block = 16 query rows x 4 waves; wave w owns K-chunks
// {2w, 2w+1} (KC=256): Phase A adj int4 x16 (prefetched during MFMA of the
// previous chunk) + scores -> P fp16 in wave-private LDS; Phase B 8 k-steps
// x 4 col MFMAs; partials combined once via LDS at the end.
// ---------------------------------------------------------------------------
constexpr int KC  = 256;
constexpr int PST = KC + 8;

__global__ __launch_bounds__(256, 3) void k_attn(
    const int* __restrict__ adj,
    const _Float16* __restrict__ Whh2,   // [B][N/8][64][8]
    const float* __restrict__ Wh1, const float* __restrict__ Wh2,
    float* __restrict__ hp)
{
    __shared__ __align__(16) char smem[4 * 16 * PST * 2];   // 33792 B
    __shared__ float ssum[4][16];
    __shared__ float redb[4];

    const int tid  = threadIdx.x;
    const int lane = tid & 63;
    const int w    = tid >> 6;
    const int b    = blockIdx.x >> 7;
    const int i0   = (blockIdx.x & 127) * 16;
    const int m    = lane & 15;
    const int q    = lane >> 4;

    _Float16* __restrict__ Pw = (_Float16*)smem + w * 16 * PST;

    // Wh2 register cache for this wave's 2 chunks
    const f32x4* __restrict__ w2v = (const f32x4*)(Wh2 + (size_t)b * NN);
    f32x4 wv[2];
    #pragma unroll
    for (int t = 0; t < 2; ++t) wv[t] = w2v[(2 * w + t) * 64 + lane];

    // batch-wide max of Wh2 (block covers all 2048 via the 4 waves)
    float mx = fmaxf(fmaxf(wv[0][0], wv[0][1]), fmaxf(wv[0][2], wv[0][3]));
    mx = fmaxf(mx, fmaxf(fmaxf(wv[1][0], wv[1][1]), fmaxf(wv[1][2], wv[1][3])));
    mx = wave_max(mx);
    if (lane == 0) redb[w] = mx;
    __syncthreads();
    const float M = fmaxf(fmaxf(redb[0], redb[1]), fmaxf(redb[2], redb[3]));

    float w1r[16], cr[16];
    #pragma unroll
    for (int r = 0; r < 16; ++r) {
        w1r[r] = Wh1[b * NN + i0 + r];
        const float t0 = w1r[r] + M;
        cr[r] = (t0 > 0.f) ? t0 : SLOPE * t0;   // exact row upper bound (lrelu monotone)
    }

    const int* __restrict__ abase = adj + ((size_t)b * NN + i0) * NN;
    const half8* __restrict__ Wp = (const half8*)(Whh2 + (size_t)b * NN * HD);

    float sacc[16];
    #pragma unroll
    for (int r = 0; r < 16; ++r) sacc[r] = 0.f;
    f32x4 acc[4];
    #pragma unroll
    for (int cc = 0; cc < 4; ++cc) acc[cc] = (f32x4){0.f, 0.f, 0.f, 0.f};

    // prefetch chunk 2w's adj tile
    int4 av[16];
    #pragma unroll
    for (int r = 0; r < 16; ++r)
        av[r] = *(const int4*)(abase + (size_t)r * NN + (2 * w) * KC + 4 * lane);

    #pragma unroll
    for (int t = 0; t < 2; ++t) {
        const int c = 2 * w + t;
        // ---- Phase A: scores + P chunk into wave-private LDS ----
        #pragma unroll
        for (int r = 0; r < 16; ++r) {
            const int ai[4] = {av[r].x, av[r].y, av[r].z, av[r].w};
            half4 ph;
            float s = 0.f;
            #pragma unroll
            for (int d = 0; d < 4; ++d) {
                const float tt = w1r[r] + wv[t][d];
                const float e = (tt > 0.f) ? tt : SLOPE * tt;
                const float p = ai[d] ? __expf(e - cr[r]) : 0.f;
                s += p;
                ph[d] = (_Float16)p;
            }
            sacc[r] += s;
            *(half4*)&Pw[r * PST + 4 * lane] = ph;
        }
        // prefetch next chunk's adj while MFMA section runs
        if (t == 0) {
            #pragma unroll
            for (int r = 0; r < 16; ++r)
                av[r] = *(const int4*)(abase + (size_t)r * NN + (2 * w + 1) * KC + 4 * lane);
        }
        __syncthreads();   // uniform across waves (same trip count)

        // ---- Phase B: partial 16x64 += P[16 x 256] @ Wh[256 x 64] ----
        #pragma unroll
        for (int k8 = 0; k8 < 8; ++k8) {
            const half8 a8 = *(const half8*)&Pw[m * PST + k8 * 32 + q * 8];
            #pragma unroll
            for (int cc = 0; cc < 4; ++cc) {
                const half8 b8 = Wp[(size_t)(c * 32 + k8 * 4 + q) * 64 + cc * 16 + m];
                acc[cc] = __builtin_amdgcn_mfma_f32_16x16x32_f16(a8, b8, acc[cc], 0, 0, 0);
            }
        }
        __syncthreads();   // WAR guard before next chunk's P writes
    }

    // ---- combine partials across the 4 waves ----
    #pragma unroll
    for (int r = 0; r < 16; ++r) {
        const float s = wave_sum(sacc[r]);
        if (lane == 0) ssum[w][r] = s;
    }
    float* __restrict__ accb = (float*)smem;     // aliases dead P region
    #pragma unroll
    for (int cc = 0; cc < 4; ++cc)
        *(f32x4*)&accb[((w * 64 + lane) * 4 + cc) * 4] = acc[cc];
    __syncthreads();

    f32x4 tot = (f32x4){0.f, 0.f, 0.f, 0.f};
    #pragma unroll
    for (int wp = 0; wp < 4; ++wp) {
        const f32x4 t4 = *(const f32x4*)&accb[((wp * 64 + lane) * 4 + w) * 4];
        tot[0] += t4[0]; tot[1] += t4[1]; tot[2] += t4[2]; tot[3] += t4[3];
    }
    #pragma unroll
    for (int r2 = 0; r2 < 4; ++r2) {
        const int irow = q * 4 + r2;
        const float S = ssum[0][irow] + ssum[1][irow] + ssum[2][irow] + ssum[3][irow];
        hp[((size_t)b * NN + i0 + irow) * HD + w * 16 + m] = tot[r2] / S;
    }
}

// ---------------------------------------------------------------------------
extern "C" void kernel_launch(void* const* d_in, const int* in_sizes, int n_in,
                              void* d_out, int out_size, void* d_ws, size_t ws_size,
                              hipStream_t stream) {
    const int*   adj = (const int*)d_in[0];
    const float* x   = (const float*)d_in[1];
    const float* h   = (const float*)d_in[2];
    const float* X2H = (const float*)d_in[3];
    const float* H2H = (const float*)d_in[4];
    const float* a   = (const float*)d_in[5];

    float* out = (float*)d_out;
    float* hp  = out;                              // h_prime [8][2048][64]
    float* Wh  = out + (size_t)BB * NN * HD;       // Wh      [8][2048][64]

    float*    Wh1  = (float*)d_ws;                           // [B*N]
    float*    Wh2  = Wh1 + BB * NN;                          // [B*N]
    _Float16* Whh2 = (_Float16*)(Wh2 + BB * NN);             // [B][N/8][64][8]
    _Float16* Wt   = Whh2 + (size_t)BB * NN * HD;            // [256][192]

    k_prep<<<dim3(64), dim3(256), 0, stream>>>(X2H, H2H, Wt);
    k_gates<<<dim3((BB * NN) / 16), dim3(256), 0, stream>>>(
        x, h, Wt, a, Wh, Whh2, Wh1, Wh2);
    k_attn<<<dim3(BB * (NN / 16)), dim3(256), 0, stream>>>(
        adj, Whh2, Wh1, Wh2, hp);
}

// Round 7
// 239.282 us; speedup vs baseline: 1.4088x; 1.2082x over previous
//
#include <hip/hip_runtime.h>

// Problem constants (match reference)
constexpr int BB  = 8;
constexpr int NN  = 2048;
constexpr int IND = 128;
constexpr int HD  = 64;
constexpr float LN_EPS = 1e-5f;
constexpr float SLOPE  = 0.2f;

typedef _Float16 half8 __attribute__((ext_vector_type(8)));
typedef _Float16 half4 __attribute__((ext_vector_type(4)));
typedef float    f32x4 __attribute__((ext_vector_type(4)));

__device__ __forceinline__ float wave_sum(float v) {
    #pragma unroll
    for (int off = 32; off > 0; off >>= 1) v += __shfl_xor(v, off);
    return v;
}
__device__ __forceinline__ float wave_max(float v) {
    #pragma unroll
    for (int off = 32; off > 0; off >>= 1) v = fmaxf(v, __shfl_xor(v, off));
    return v;
}

// ---------------------------------------------------------------------------
// Kernel 0 (unchanged): build Wt[256 cols][192 k] fp16, k-major.
//   [0,64): r-gate  [64,128): i-gate  [128,192): i_n (x only)  [192,256): h_n (h only)
// ---------------------------------------------------------------------------
__global__ void k_prep(const float* __restrict__ X2H, const float* __restrict__ H2H,
                       _Float16* __restrict__ Wt)
{
    const int tot = 256 * 192;
    for (int idx = blockIdx.x * 256 + threadIdx.x; idx < tot; idx += gridDim.x * 256) {
        const int col = idx / 192, k = idx % 192;
        float v;
        if (col < 128)       v = (k < 128) ? X2H[(size_t)k * 192 + col]
                                           : H2H[(size_t)(k - 128) * 192 + col];
        else if (col < 192)  v = (k < 128) ? X2H[(size_t)k * 192 + col] : 0.f;
        else                 v = (k >= 128) ? H2H[(size_t)(k - 128) * 192 + (col - 64)] : 0.f;
        Wt[idx] = (_Float16)v;
    }
}

// ---------------------------------------------------------------------------
// Kernel 1 (unchanged from R6): gates via fp16 MFMA, 16 rows x 4 waves.
// ---------------------------------------------------------------------------
__global__ __launch_bounds__(256, 4) void k_gates(
    const float* __restrict__ x, const float* __restrict__ h,
    const _Float16* __restrict__ Wt, const float* __restrict__ a,
    float* __restrict__ Wh_out, _Float16* __restrict__ Whh2,
    float* __restrict__ Wh1, float* __restrict__ Wh2)
{
    __shared__ float gbuf[16][260];

    const int tid = threadIdx.x, lane = tid & 63, w = tid >> 6;
    const int m = lane & 15, q = lane >> 4;
    const int row0 = blockIdx.x * 16;

    f32x4 acc[4];
    #pragma unroll
    for (int ct = 0; ct < 4; ++ct) acc[ct] = (f32x4){0.f, 0.f, 0.f, 0.f};

    #pragma unroll
    for (int kc = 0; kc < 6; ++kc) {
        half8 a8;
        if (kc < 4) {
            const float* xp = x + (size_t)(row0 + m) * IND + kc * 32 + q * 8;
            const f32x4 v0 = *(const f32x4*)xp;
            const f32x4 v1 = *(const f32x4*)(xp + 4);
            #pragma unroll
            for (int j = 0; j < 4; ++j) { a8[j] = (_Float16)v0[j]; a8[4 + j] = (_Float16)v1[j]; }
        } else {
            const float* hp_ = h + (size_t)(row0 + m) * HD + (kc - 4) * 32 + q * 8;
            const f32x4 v0 = *(const f32x4*)hp_;
            const f32x4 v1 = *(const f32x4*)(hp_ + 4);
            #pragma unroll
            for (int j = 0; j < 4; ++j) { a8[j] = (_Float16)v0[j]; a8[4 + j] = (_Float16)v1[j]; }
        }
        #pragma unroll
        for (int ct = 0; ct < 4; ++ct) {
            const half8 b8 = *(const half8*)(Wt + ((size_t)(w * 64 + ct * 16 + m) * 192 + kc * 32 + q * 8));
            acc[ct] = __builtin_amdgcn_mfma_f32_16x16x32_f16(a8, b8, acc[ct], 0, 0, 0);
        }
    }

    #pragma unroll
    for (int ct = 0; ct < 4; ++ct)
        #pragma unroll
        for (int r2 = 0; r2 < 4; ++r2)
            gbuf[q * 4 + r2][w * 64 + ct * 16 + m] = acc[ct][r2];
    __syncthreads();

    const float a0 = a[lane], a1 = a[64 + lane];
    half4 p4;
    const int grow0 = row0 + w * 4;
    #pragma unroll
    for (int r = 0; r < 4; ++r) {
        const int row = w * 4 + r;
        const int grow = row0 + row;
        const float g0 = gbuf[row][lane];
        const float g1 = gbuf[row][64 + lane];
        const float g2 = gbuf[row][128 + lane];
        const float g3 = gbuf[row][192 + lane];
        const float rg = 1.f / (1.f + __expf(-g0));
        const float ig = 1.f / (1.f + __expf(-g1));
        const float irh = g2 + rg * g3;
        const float mu = wave_sum(irh) * (1.f / 64.f);
        const float dv = irh - mu;
        const float var = wave_sum(dv * dv) * (1.f / 64.f);
        const float ng = tanhf(dv * rsqrtf(var + LN_EPS));
        const float hr = h[(size_t)grow * HD + lane];
        const float wh = ng + ig * (hr - ng);
        Wh_out[(size_t)grow * HD + lane] = wh;
        p4[r] = (_Float16)wh;
        const float d1 = wave_sum(wh * a0);
        const float d2 = wave_sum(wh * a1);
        if (lane == 0) { Wh1[grow] = d1; Wh2[grow] = d2; }
    }
    *(half4*)(Whh2 + ((size_t)(grow0 >> 3) * 64 + lane) * 8 + (w & 1) * 4) = p4;
}

// ---------------------------------------------------------------------------
// Kernel 2: attention.  Block = 512 threads (8 waves) x 16 query rows.
// Wave w owns K-chunk w (KC=256) END-TO-END: its whole adj share (16 rows x
// 1KB) streams through a double-buffered front-loaded burst, so all 16
// resident waves/CU keep adj demand in flight for most of the kernel
// (vs R6's 20% duty cycle).  Phase B: K-split MFMA on the wave's own P
// slice; 8-way partial combine via LDS (stride-17 pad, conflict-free).
// LDS 68 KB -> 2 blocks/CU = 16 waves/CU.
// ---------------------------------------------------------------------------
constexpr int KC  = 256;
constexpr int PST = KC + 8;    // 264

__global__ __launch_bounds__(512, 4) void k_attn(
    const int* __restrict__ adj,
    const _Float16* __restrict__ Whh2,   // [B][N/8][64][8]
    const float* __restrict__ Wh1, const float* __restrict__ Wh2,
    float* __restrict__ hp)
{
    __shared__ __align__(16) _Float16 Pall[8 * 16 * PST];   // 67584 B
    __shared__ float ssum[8][16];
    __shared__ float redb[8];

    const int tid  = threadIdx.x;
    const int lane = tid & 63;
    const int w    = tid >> 6;               // wave id = chunk id (0..7)
    const int b    = blockIdx.x >> 7;
    const int i0   = (blockIdx.x & 127) * 16;
    const int m    = lane & 15;
    const int q    = lane >> 4;

    _Float16* __restrict__ Pw = Pall + w * 16 * PST;

    // Wh2 cache for this wave's chunk: cols w*256 + 4*lane + d
    const f32x4 wv = ((const f32x4*)(Wh2 + (size_t)b * NN))[w * 64 + lane];

    // batch-wide max of Wh2 (8 waves cover all 2048)
    float mx = fmaxf(fmaxf(wv[0], wv[1]), fmaxf(wv[2], wv[3]));
    mx = wave_max(mx);
    if (lane == 0) redb[w] = mx;
    __syncthreads();
    float M = redb[0];
    #pragma unroll
    for (int i = 1; i < 8; ++i) M = fmaxf(M, redb[i]);

    float w1r[16];
    #pragma unroll
    for (int r = 0; r < 16; ++r) w1r[r] = Wh1[b * NN + i0 + r];

    // adj: row r of this tile, this wave's chunk, this lane's 4 cols
    const int* __restrict__ abase = adj + ((size_t)b * NN + i0) * NN + w * KC + 4 * lane;

    // ---- Phase A: double-buffered adj stream -> P slice ----
    int4 buf0[4], buf1[4];
    #pragma unroll
    for (int r = 0; r < 4; ++r) buf0[r] = *(const int4*)(abase + (size_t)r * NN);
    #pragma unroll
    for (int r = 0; r < 4; ++r) buf1[r] = *(const int4*)(abase + (size_t)(4 + r) * NN);

    #pragma unroll
    for (int g = 0; g < 4; ++g) {
        #pragma unroll
        for (int rr = 0; rr < 4; ++rr) {
            const int r = g * 4 + rr;
            const int4 av = (g & 1) ? buf1[rr] : buf0[rr];
            const int ai[4] = {av.x, av.y, av.z, av.w};
            const float t0 = w1r[r] + M;
            const float c  = (t0 > 0.f) ? t0 : SLOPE * t0;   // exact row upper bound
            half4 ph;
            float s = 0.f;
            #pragma unroll
            for (int d = 0; d < 4; ++d) {
                const float t = w1r[r] + wv[d];
                const float e = (t > 0.f) ? t : SLOPE * t;
                const float p = ai[d] ? __expf(e - c) : 0.f;
                s += p;
                ph[d] = (_Float16)p;
            }
            s = wave_sum(s);
            if (lane == 0) ssum[w][r] = s;
            *(half4*)&Pw[r * PST + 4 * lane] = ph;           // ds_write_b64
        }
        // refill the buffer just consumed with rows 2 groups ahead
        if (g + 2 < 4) {
            #pragma unroll
            for (int rr = 0; rr < 4; ++rr) {
                int4 nv = *(const int4*)(abase + (size_t)((g + 2) * 4 + rr) * NN);
                if (g & 1) buf1[rr] = nv; else buf0[rr] = nv;
            }
        }
    }
    __syncthreads();

    // ---- Phase B: partial 16x64 += P_w[16 x 256] @ Wh[chunk w][256 x 64] ----
    const half8* __restrict__ Wp = (const half8*)(Whh2 + (size_t)b * NN * HD);
    f32x4 acc[4];
    #pragma unroll
    for (int cc = 0; cc < 4; ++cc) acc[cc] = (f32x4){0.f, 0.f, 0.f, 0.f};

    #pragma unroll
    for (int k8 = 0; k8 < 8; ++k8) {
        const half8 a8 = *(const half8*)&Pw[m * PST + k8 * 32 + q * 8];
        #pragma unroll
        for (int cc = 0; cc < 4; ++cc) {
            const half8 b8 = Wp[(size_t)(w * 32 + k8 * 4 + q) * 64 + cc * 16 + m];
            acc[cc] = __builtin_amdgcn_mfma_f32_16x16x32_f16(a8, b8, acc[cc], 0, 0, 0);
        }
    }
    __syncthreads();   // all Phase-B ds_reads done before aliasing P region

    // ---- 8-way partial combine (alias dead P region, stride-17 pad) ----
    float* __restrict__ accb = (float*)Pall;     // [8*64][17] used sparsely
    #pragma unroll
    for (int cc = 0; cc < 4; ++cc)
        *(f32x4*)&accb[(w * 64 + lane) * 17 + cc * 4] = acc[cc];
    __syncthreads();

    if (w < 4) {
        f32x4 tot = (f32x4){0.f, 0.f, 0.f, 0.f};
        #pragma unroll
        for (int wp = 0; wp < 8; ++wp) {
            const f32x4 t4 = *(const f32x4*)&accb[(wp * 64 + lane) * 17 + w * 4];
            tot[0] += t4[0]; tot[1] += t4[1]; tot[2] += t4[2]; tot[3] += t4[3];
        }
        #pragma unroll
        for (int r2 = 0; r2 < 4; ++r2) {
            const int irow = q * 4 + r2;
            float S = 0.f;
            #pragma unroll
            for (int wp = 0; wp < 8; ++wp) S += ssum[wp][irow];
            hp[((size_t)b * NN + i0 + irow) * HD + w * 16 + m] = tot[r2] / S;
        }
    }
}

// ---------------------------------------------------------------------------
extern "C" void kernel_launch(void* const* d_in, const int* in_sizes, int n_in,
                              void* d_out, int out_size, void* d_ws, size_t ws_size,
                              hipStream_t stream) {
    const int*   adj = (const int*)d_in[0];
    const float* x   = (const float*)d_in[1];
    const float* h   = (const float*)d_in[2];
    const float* X2H = (const float*)d_in[3];
    const float* H2H = (const float*)d_in[4];
    const float* a   = (const float*)d_in[5];

    float* out = (float*)d_out;
    float* hp  = out;                              // h_prime [8][2048][64]
    float* Wh  = out + (size_t)BB * NN * HD;       // Wh      [8][2048][64]

    float*    Wh1  = (float*)d_ws;                           // [B*N]
    float*    Wh2  = Wh1 + BB * NN;                          // [B*N]
    _Float16* Whh2 = (_Float16*)(Wh2 + BB * NN);             // [B][N/8][64][8]
    _Float16* Wt   = Whh2 + (size_t)BB * NN * HD;            // [256][192]

    k_prep<<<dim3(64), dim3(256), 0, stream>>>(X2H, H2H, Wt);
    k_gates<<<dim3((BB * NN) / 16), dim3(256), 0, stream>>>(
        x, h, Wt, a, Wh, Whh2, Wh1, Wh2);
    k_attn<<<dim3(BB * (NN / 16)), dim3(512), 0, stream>>>(
        adj, Whh2, Wh1, Wh2, hp);
}